// Round 1
// baseline (6104.465 us; speedup 1.0000x reference)
//
#include <hip/hip_runtime.h>

#define NN 100000
#define NE 1600000
#define NG 512
#define HIDC 128
#define OUTS 8128

__device__ __forceinline__ void atomAddF(float* p, float v) {
    unsafeAtomicAdd(p, v);  // global_atomic_add_f32 on gfx950
}

// ---- degree: deg[dst] += 1 ----
__global__ __launch_bounds__(256) void k_deg(const int* __restrict__ dst, float* __restrict__ deg) {
    int e = blockIdx.x * 256 + threadIdx.x;
    if (e < NE) atomAddF(&deg[dst[e]], 1.0f);
}

// ---- dinv = rsqrt(deg + 1) in place ----
__global__ __launch_bounds__(256) void k_dinv(float* __restrict__ deg) {
    int i = blockIdx.x * 256 + threadIdx.x;
    if (i < NN) deg[i] = rsqrtf(deg[i] + 1.0f);
}

// ---- out[m][n] = dinv[m] * sum_k A[m][k] * W[k][n];  N=128, K in {64,128} ----
// block = 256 threads = 16 rows x 16 colgroups(8 cols each); grid = M/16
template<int K>
__global__ __launch_bounds__(256) void k_gemm_scale(const float* __restrict__ A,
        const float* __restrict__ W, const float* __restrict__ dinv,
        float* __restrict__ out) {
    __shared__ __align__(16) float Wlds[64 * 128];
    int r  = threadIdx.x >> 4;
    int cg = threadIdx.x & 15;
    long row = (long)blockIdx.x * 16 + r;
    const float* a = &A[row * K];
    int c0 = cg * 8;
    float ax0=0,ax1=0,ax2=0,ax3=0,ay0=0,ay1=0,ay2=0,ay3=0;
    for (int kt = 0; kt < K; kt += 64) {
        __syncthreads();
        for (int i = threadIdx.x * 4; i < 64 * 128; i += 256 * 4)
            *(float4*)&Wlds[i] = *(const float4*)&W[kt * 128 + i];
        __syncthreads();
        #pragma unroll
        for (int kk = 0; kk < 64; ++kk) {
            float av = a[kt + kk];
            float4 w0 = *(const float4*)&Wlds[kk * 128 + c0];
            float4 w1 = *(const float4*)&Wlds[kk * 128 + c0 + 4];
            ax0 += av * w0.x; ax1 += av * w0.y; ax2 += av * w0.z; ax3 += av * w0.w;
            ay0 += av * w1.x; ay1 += av * w1.y; ay2 += av * w1.z; ay3 += av * w1.w;
        }
    }
    float d = dinv[row];
    float4 o0 = { ax0 * d, ax1 * d, ax2 * d, ax3 * d };
    float4 o1 = { ay0 * d, ay1 * d, ay2 * d, ay3 * d };
    *(float4*)&out[row * 128 + c0]     = o0;
    *(float4*)&out[row * 128 + c0 + 4] = o1;
}

// ---- s[dst] += g[src] over all edges; 8 edges/block, 32 lanes/edge x 4ch ----
__global__ __launch_bounds__(256) void k_scatter(const int* __restrict__ src,
        const int* __restrict__ dst, const float* __restrict__ g, float* __restrict__ s) {
    int e  = blockIdx.x * 8 + (threadIdx.x >> 5);
    int cg = threadIdx.x & 31;
    int sv = src[e], dv = dst[e];
    float4 v = *(const float4*)&g[(long)sv * 128 + cg * 4];
    float* sp = &s[(long)dv * 128 + cg * 4];
    atomAddF(sp + 0, v.x); atomAddF(sp + 1, v.y);
    atomAddF(sp + 2, v.z); atomAddF(sp + 3, v.w);
}

// ---- out = relu(s * dinv[row] + b[col]) ----
__global__ __launch_bounds__(256) void k_post(const float* __restrict__ s,
        const float* __restrict__ dinv, const float* __restrict__ b, float* __restrict__ out) {
    long i = (long)blockIdx.x * 256 + threadIdx.x;  // element4 index, NN*32 total
    long row = i >> 5; int cg = (int)(i & 31);
    float4 v = *(const float4*)&s[row * 128 + cg * 4];
    float d = dinv[row];
    float4 bb = *(const float4*)&b[cg * 4];
    float4 o;
    o.x = fmaxf(v.x * d + bb.x, 0.f);
    o.y = fmaxf(v.y * d + bb.y, 0.f);
    o.z = fmaxf(v.z * d + bb.z, 0.f);
    o.w = fmaxf(v.w * d + bb.w, 0.f);
    *(float4*)&out[row * 128 + cg * 4] = o;
}

// ---- pooling sums + counts ----
__global__ __launch_bounds__(256) void k_pool(const float* __restrict__ h,
        const int* __restrict__ batch, float* __restrict__ sums, float* __restrict__ cnt) {
    int node = blockIdx.x * 8 + (threadIdx.x >> 5);
    int cg = threadIdx.x & 31;
    int gph = batch[node];
    float4 v = *(const float4*)&h[(long)node * 128 + cg * 4];
    float* sp = &sums[gph * 128 + cg * 4];
    atomAddF(sp + 0, v.x); atomAddF(sp + 1, v.y);
    atomAddF(sp + 2, v.z); atomAddF(sp + 3, v.w);
    if (cg == 0) atomAddF(&cnt[gph], 1.0f);
}

// ---- mean, mu/logvar heads, reparameterise ----
__global__ __launch_bounds__(64) void k_head(const float* __restrict__ sums,
        const float* __restrict__ cnt, const float* __restrict__ Wmu, const float* __restrict__ bmu,
        const float* __restrict__ Wlv, const float* __restrict__ blv,
        const float* __restrict__ eps, float* __restrict__ mu_o, float* __restrict__ lv_o,
        float* __restrict__ z) {
    __shared__ float row[128];
    int g = blockIdx.x, t = threadIdx.x;
    float inv = 1.0f / fmaxf(cnt[g], 1.0f);
    row[t]      = sums[g * 128 + t] * inv;
    row[t + 64] = sums[g * 128 + t + 64] * inv;
    __syncthreads();
    float mu = bmu[t], lv = blv[t];
    for (int k = 0; k < 128; ++k) {
        float rv = row[k];
        mu += rv * Wmu[k * 64 + t];
        lv += rv * Wlv[k * 64 + t];
    }
    mu_o[g * 64 + t] = mu;
    lv_o[g * 64 + t] = lv;
    z[g * 64 + t] = mu + eps[g * 64 + t] * expf(0.5f * lv);
}

// ---- small MLP layer: out[m] = relu(A[m] @ W + b), N=128 ----
__global__ __launch_bounds__(128) void k_mlp(const float* __restrict__ A, int K,
        const float* __restrict__ W, const float* __restrict__ b, float* __restrict__ out) {
    __shared__ float row[128];
    int m = blockIdx.x, t = threadIdx.x;
    if (t < K) row[t] = A[m * K + t];
    __syncthreads();
    float acc = b[t];
    for (int k = 0; k < K; ++k) acc += row[k] * W[k * 128 + t];
    out[m * 128 + t] = fmaxf(acc, 0.f);
}

// ---- probs = sigmoid(A @ D3 + d3), M=512 K=128 N=8128 ----
__global__ __launch_bounds__(256) void k_dec3(const float* __restrict__ A,
        const float* __restrict__ W, const float* __restrict__ b, float* __restrict__ out) {
    __shared__ float row[128];
    int m = blockIdx.y;
    if (threadIdx.x < 128) row[threadIdx.x] = A[m * 128 + threadIdx.x];
    __syncthreads();
    int c0 = blockIdx.x * 1024 + threadIdx.x * 4;
    if (c0 >= OUTS) return;
    float4 acc = *(const float4*)&b[c0];
    for (int k = 0; k < 128; ++k) {
        float av = row[k];
        float4 w = *(const float4*)&W[k * OUTS + c0];
        acc.x += av * w.x; acc.y += av * w.y; acc.z += av * w.z; acc.w += av * w.w;
    }
    float4 o;
    o.x = 1.f / (1.f + expf(-acc.x));
    o.y = 1.f / (1.f + expf(-acc.y));
    o.z = 1.f / (1.f + expf(-acc.z));
    o.w = 1.f / (1.f + expf(-acc.w));
    *(float4*)&out[(long)m * OUTS + c0] = o;
}

// ---- build symmetric adjacency from upper-tri probs ----
__global__ __launch_bounds__(256) void k_adj(const float* __restrict__ probs, float* __restrict__ adj) {
    int t = blockIdx.x * 256 + threadIdx.x;        // el4 index, 512*16384/4 total
    int g = t >> 12;
    int rem = t & 4095;
    int r = rem >> 5;
    int c0 = (rem & 31) * 4;
    const float* pg = &probs[g * OUTS];
    float4 o;
    float* op = (float*)&o;
    #pragma unroll
    for (int j = 0; j < 4; ++j) {
        int c = c0 + j;
        if (c == r) { op[j] = 0.f; continue; }
        int a = c < r ? c : r;
        int b = c < r ? r : c;
        int k = a * (255 - a) / 2 + (b - a - 1);
        op[j] = pg[k];
    }
    *(float4*)&adj[(long)t * 4] = o;
}

extern "C" void kernel_launch(void* const* d_in, const int* in_sizes, int n_in,
                              void* d_out, int out_size, void* d_ws, size_t ws_size,
                              hipStream_t stream) {
    const float* x   = (const float*)d_in[0];
    const int*   ei  = (const int*)d_in[1];
    const int* batch = (const int*)d_in[2];
    const float* eps = (const float*)d_in[3];
    const float* W1  = (const float*)d_in[4];
    const float* b1  = (const float*)d_in[5];
    const float* W2  = (const float*)d_in[6];
    const float* b2  = (const float*)d_in[7];
    const float* Wmu = (const float*)d_in[8];
    const float* bmu = (const float*)d_in[9];
    const float* Wlv = (const float*)d_in[10];
    const float* blv = (const float*)d_in[11];
    const float* D1  = (const float*)d_in[12];
    const float* d1  = (const float*)d_in[13];
    const float* D2  = (const float*)d_in[14];
    const float* d2  = (const float*)d_in[15];
    const float* D3  = (const float*)d_in[16];
    const float* d3  = (const float*)d_in[17];

    float* ws   = (float*)d_ws;
    float* deg  = ws;                       // 100000 (becomes dinv)
    float* bufA = ws + 102400;              // 12.8M floats
    float* bufB = bufA + 12800000;          // 12.8M floats
    // decoder scratch aliases bufA (free by then)
    float* hg    = bufA;                    // 65536
    float* cnt   = bufA + 65536;            // 512
    float* zbuf  = bufA + 66048;            // 32768
    float* p1    = bufA + 98816;            // 65536
    float* p2    = bufA + 164352;           // 65536
    float* probs = bufA + 229888;           // 4161536

    float* out  = (float*)d_out;
    float* mu_o = out + 8388608;
    float* lv_o = mu_o + 32768;

    const int* esrc = ei;
    const int* edst = ei + NE;

    hipMemsetAsync(deg, 0, NN * sizeof(float), stream);
    k_deg<<<(NE + 255) / 256, 256, 0, stream>>>(edst, deg);
    k_dinv<<<(NN + 255) / 256, 256, 0, stream>>>(deg);

    // ---- conv1: g1 = (x@W1)*dinv -> A; s1 = g1 + scatter -> B; h1 = relu(s1*dinv+b1) -> A
    k_gemm_scale<64><<<NN / 16, 256, 0, stream>>>(x, W1, deg, bufA);
    hipMemcpyAsync(bufB, bufA, (size_t)NN * 128 * 4, hipMemcpyDeviceToDevice, stream);
    k_scatter<<<NE / 8, 256, 0, stream>>>(esrc, edst, bufA, bufB);
    k_post<<<NN * 32 / 256, 256, 0, stream>>>(bufB, deg, b1, bufA);

    // ---- conv2: g2 = (h1@W2)*dinv -> B; s2 -> A; h2 = relu(s2*dinv+b2) -> B
    k_gemm_scale<128><<<NN / 16, 256, 0, stream>>>(bufA, W2, deg, bufB);
    hipMemcpyAsync(bufA, bufB, (size_t)NN * 128 * 4, hipMemcpyDeviceToDevice, stream);
    k_scatter<<<NE / 8, 256, 0, stream>>>(esrc, edst, bufB, bufA);
    k_post<<<NN * 32 / 256, 256, 0, stream>>>(bufA, deg, b2, bufB);

    // ---- pool + heads + reparameterise
    hipMemsetAsync(hg, 0, 66048 * sizeof(float), stream);
    k_pool<<<NN * 32 / 256, 256, 0, stream>>>(bufB, batch, hg, cnt);
    k_head<<<NG, 64, 0, stream>>>(hg, cnt, Wmu, bmu, Wlv, blv, eps, mu_o, lv_o, zbuf);

    // ---- decoder
    k_mlp<<<NG, 128, 0, stream>>>(zbuf, 64, D1, d1, p1);
    k_mlp<<<NG, 128, 0, stream>>>(p1, 128, D2, d2, p2);
    dim3 g3(8, NG);
    k_dec3<<<g3, 256, 0, stream>>>(p2, D3, d3, probs);
    k_adj<<<8192, 256, 0, stream>>>(probs, out);
}

// Round 2
// 738.683 us; speedup vs baseline: 8.2640x; 8.2640x over previous
//
#include <hip/hip_runtime.h>

#define NN 100000
#define NE 1600000
#define NG 512
#define OUTS 8128

__device__ __forceinline__ void atomAddF(float* p, float v) {
    unsafeAtomicAdd(p, v);
}

// ---- int degree: cnt[dst] += 1 ----
__global__ __launch_bounds__(256) void k_deg(const int* __restrict__ dst, int* __restrict__ cnt) {
    int e = blockIdx.x * 256 + threadIdx.x;
    if (e < NE) atomicAdd(&cnt[dst[e]], 1);
}

// ---- dinv = rsqrt(deg + 1) ----
__global__ __launch_bounds__(256) void k_dinv(const int* __restrict__ cnt, float* __restrict__ dinv) {
    int i = blockIdx.x * 256 + threadIdx.x;
    if (i < NN) dinv[i] = rsqrtf((float)cnt[i] + 1.0f);
}

// ---- hierarchical exclusive scan: per-block (1024 elems) ----
__global__ __launch_bounds__(256) void k_scanA(const int* __restrict__ cnt, int* __restrict__ pre,
                                               int* __restrict__ bsum) {
    __shared__ int lds[256];
    int base = blockIdx.x * 1024 + threadIdx.x * 4;
    int v0 = 0, v1 = 0, v2 = 0, v3 = 0;
    if (base + 3 < NN) {
        int4 c = *(const int4*)&cnt[base];
        v0 = c.x; v1 = c.y; v2 = c.z; v3 = c.w;
    } else {
        if (base + 0 < NN) v0 = cnt[base + 0];
        if (base + 1 < NN) v1 = cnt[base + 1];
        if (base + 2 < NN) v2 = cnt[base + 2];
    }
    int s = v0 + v1 + v2 + v3;
    lds[threadIdx.x] = s;
    __syncthreads();
    for (int off = 1; off < 256; off <<= 1) {
        int t = (threadIdx.x >= off) ? lds[threadIdx.x - off] : 0;
        __syncthreads();
        lds[threadIdx.x] += t;
        __syncthreads();
    }
    int excl = lds[threadIdx.x] - s;
    if (threadIdx.x == 255) bsum[blockIdx.x] = lds[255];
    if (base < NN) {
        int p0 = excl, p1 = p0 + v0, p2 = p1 + v1, p3 = p2 + v2;
        if (base + 3 < NN) { int4 o = {p0, p1, p2, p3}; *(int4*)&pre[base] = o; }
        else {
            pre[base] = p0;
            if (base + 1 < NN) pre[base + 1] = p1;
            if (base + 2 < NN) pre[base + 2] = p2;
        }
    }
}

__global__ void k_scanB(const int* __restrict__ bsum, int* __restrict__ boff, int nb) {
    __shared__ int lds[128];
    int v = (threadIdx.x < nb) ? bsum[threadIdx.x] : 0;
    lds[threadIdx.x] = v;
    __syncthreads();
    for (int off = 1; off < 128; off <<= 1) {
        int t = (threadIdx.x >= off) ? lds[threadIdx.x - off] : 0;
        __syncthreads();
        lds[threadIdx.x] += t;
        __syncthreads();
    }
    if (threadIdx.x < nb) boff[threadIdx.x] = lds[threadIdx.x] - v;
}

__global__ __launch_bounds__(256) void k_scanC(int* __restrict__ pre, const int* __restrict__ boff) {
    int i = blockIdx.x * 256 + threadIdx.x;
    if (i < NN) pre[i] += boff[i >> 10];
}

// ---- counting-sort fill of CSR col indices ----
__global__ __launch_bounds__(256) void k_fill(const int* __restrict__ src, const int* __restrict__ dst,
        const int* __restrict__ rowptr, int* __restrict__ cur, int* __restrict__ colidx) {
    int e = blockIdx.x * 256 + threadIdx.x;
    if (e >= NE) return;
    int d = dst[e];
    int pos = atomicAdd(&cur[d], 1);
    colidx[rowptr[d] + pos] = src[e];
}

// ---- segment ends from sorted batch ----
__global__ __launch_bounds__(256) void k_segend(const int* __restrict__ batch, int* __restrict__ seg_end) {
    int i = blockIdx.x * 256 + threadIdx.x;
    if (i >= NN) return;
    int b = batch[i];
    int bn = (i == NN - 1) ? NG : batch[i + 1];
    for (int g = b; g < bn; ++g) seg_end[g] = i + 1;
    if (i == 0) {
        for (int g = 0; g < b; ++g) seg_end[g] = 0;
    }
}

// ---- out[m][n] = dinv[m] * sum_k A[m][k] * W[k][n];  N=128 ----
template<int K>
__global__ __launch_bounds__(256) void k_gemm_scale(const float* __restrict__ A,
        const float* __restrict__ W, const float* __restrict__ dinv,
        float* __restrict__ out) {
    __shared__ __align__(16) float Wlds[64 * 128];
    int r  = threadIdx.x >> 4;
    int cg = threadIdx.x & 15;
    long row = (long)blockIdx.x * 16 + r;
    const float* a = &A[row * K];
    int c0 = cg * 8;
    float ax0=0,ax1=0,ax2=0,ax3=0,ay0=0,ay1=0,ay2=0,ay3=0;
    for (int kt = 0; kt < K; kt += 64) {
        __syncthreads();
        for (int i = threadIdx.x * 4; i < 64 * 128; i += 256 * 4)
            *(float4*)&Wlds[i] = *(const float4*)&W[kt * 128 + i];
        __syncthreads();
        #pragma unroll
        for (int kk = 0; kk < 64; ++kk) {
            float av = a[kt + kk];
            float4 w0 = *(const float4*)&Wlds[kk * 128 + c0];
            float4 w1 = *(const float4*)&Wlds[kk * 128 + c0 + 4];
            ax0 += av * w0.x; ax1 += av * w0.y; ax2 += av * w0.z; ax3 += av * w0.w;
            ay0 += av * w1.x; ay1 += av * w1.y; ay2 += av * w1.z; ay3 += av * w1.w;
        }
    }
    float d = dinv[row];
    float4 o0 = { ax0 * d, ax1 * d, ax2 * d, ax3 * d };
    float4 o1 = { ay0 * d, ay1 * d, ay2 * d, ay3 * d };
    *(float4*)&out[row * 128 + c0]     = o0;
    *(float4*)&out[row * 128 + c0 + 4] = o1;
}

// ---- fused aggregate: out[n] = relu((g[n] + sum_{s in N(n)} g[s]) * dinv[n] + b) ----
// one wave (64 lanes) per node, float2 per lane
__global__ __launch_bounds__(256) void k_gather(const int* __restrict__ rowptr,
        const int* __restrict__ cnti, const int* __restrict__ colidx,
        const float* __restrict__ g, const float* __restrict__ dinv,
        const float* __restrict__ bias, float* __restrict__ out) {
    int node = blockIdx.x * 4 + (threadIdx.x >> 6);
    if (node >= NN) return;
    int lane = threadIdx.x & 63;
    float2 acc = *(const float2*)&g[(long)node * 128 + lane * 2];
    float2 acc2 = {0.f, 0.f};
    int beg = rowptr[node], n = cnti[node];
    const int* ci = colidx + beg;
    int j = 0;
    for (; j + 2 <= n; j += 2) {
        int s0 = ci[j], s1 = ci[j + 1];
        float2 a = *(const float2*)&g[(long)s0 * 128 + lane * 2];
        float2 b = *(const float2*)&g[(long)s1 * 128 + lane * 2];
        acc.x += a.x; acc.y += a.y;
        acc2.x += b.x; acc2.y += b.y;
    }
    if (j < n) {
        int s0 = ci[j];
        float2 a = *(const float2*)&g[(long)s0 * 128 + lane * 2];
        acc.x += a.x; acc.y += a.y;
    }
    acc.x += acc2.x; acc.y += acc2.y;
    float d = dinv[node];
    float2 bb = *(const float2*)&bias[lane * 2];
    float2 o = { fmaxf(fmaf(acc.x, d, bb.x), 0.f), fmaxf(fmaf(acc.y, d, bb.y), 0.f) };
    *(float2*)&out[(long)node * 128 + lane * 2] = o;
}

// ---- segmented mean pool: one block per graph, 128 ch ----
__global__ __launch_bounds__(128) void k_poolmean(const float* __restrict__ h,
        const int* __restrict__ seg_end, float* __restrict__ hg) {
    int g = blockIdx.x, t = threadIdx.x;
    int s = (g == 0) ? 0 : seg_end[g - 1];
    int e = seg_end[g];
    float acc = 0.f, acc2 = 0.f;
    int i = s;
    for (; i + 2 <= e; i += 2) {
        acc  += h[(long)i * 128 + t];
        acc2 += h[(long)(i + 1) * 128 + t];
    }
    if (i < e) acc += h[(long)i * 128 + t];
    acc += acc2;
    float inv = (e > s) ? 1.0f / (float)(e - s) : 0.f;
    hg[g * 128 + t] = acc * inv;
}

// ---- mu/logvar heads + reparameterise ----
__global__ __launch_bounds__(64) void k_head(const float* __restrict__ hg,
        const float* __restrict__ Wmu, const float* __restrict__ bmu,
        const float* __restrict__ Wlv, const float* __restrict__ blv,
        const float* __restrict__ eps, float* __restrict__ mu_o, float* __restrict__ lv_o,
        float* __restrict__ z) {
    __shared__ float row[128];
    int g = blockIdx.x, t = threadIdx.x;
    row[t]      = hg[g * 128 + t];
    row[t + 64] = hg[g * 128 + t + 64];
    __syncthreads();
    float mu = bmu[t], lv = blv[t];
    for (int k = 0; k < 128; ++k) {
        float rv = row[k];
        mu += rv * Wmu[k * 64 + t];
        lv += rv * Wlv[k * 64 + t];
    }
    mu_o[g * 64 + t] = mu;
    lv_o[g * 64 + t] = lv;
    z[g * 64 + t] = mu + eps[g * 64 + t] * expf(0.5f * lv);
}

// ---- small MLP layer: out[m] = relu(A[m] @ W + b), N=128 ----
__global__ __launch_bounds__(128) void k_mlp(const float* __restrict__ A, int K,
        const float* __restrict__ W, const float* __restrict__ b, float* __restrict__ out) {
    __shared__ float row[128];
    int m = blockIdx.x, t = threadIdx.x;
    if (t < K) row[t] = A[m * K + t];
    __syncthreads();
    float acc = b[t];
    for (int k = 0; k < K; ++k) acc += row[k] * W[k * 128 + t];
    out[m * 128 + t] = fmaxf(acc, 0.f);
}

// ---- probs = sigmoid(A @ D3 + d3), M=512 K=128 N=8128 ----
__global__ __launch_bounds__(256) void k_dec3(const float* __restrict__ A,
        const float* __restrict__ W, const float* __restrict__ b, float* __restrict__ out) {
    __shared__ float row[128];
    int m = blockIdx.y;
    if (threadIdx.x < 128) row[threadIdx.x] = A[m * 128 + threadIdx.x];
    __syncthreads();
    int c0 = blockIdx.x * 1024 + threadIdx.x * 4;
    if (c0 >= OUTS) return;
    float4 acc = *(const float4*)&b[c0];
    for (int k = 0; k < 128; ++k) {
        float av = row[k];
        float4 w = *(const float4*)&W[k * OUTS + c0];
        acc.x += av * w.x; acc.y += av * w.y; acc.z += av * w.z; acc.w += av * w.w;
    }
    float4 o;
    o.x = 1.f / (1.f + expf(-acc.x));
    o.y = 1.f / (1.f + expf(-acc.y));
    o.z = 1.f / (1.f + expf(-acc.z));
    o.w = 1.f / (1.f + expf(-acc.w));
    *(float4*)&out[(long)m * OUTS + c0] = o;
}

// ---- build symmetric adjacency from upper-tri probs ----
__global__ __launch_bounds__(256) void k_adj(const float* __restrict__ probs, float* __restrict__ adj) {
    int t = blockIdx.x * 256 + threadIdx.x;
    int g = t >> 12;
    int rem = t & 4095;
    int r = rem >> 5;
    int c0 = (rem & 31) * 4;
    const float* pg = &probs[g * OUTS];
    float4 o;
    float* op = (float*)&o;
    #pragma unroll
    for (int j = 0; j < 4; ++j) {
        int c = c0 + j;
        if (c == r) { op[j] = 0.f; continue; }
        int a = c < r ? c : r;
        int b = c < r ? r : c;
        int k = a * (255 - a) / 2 + (b - a - 1);
        op[j] = pg[k];
    }
    *(float4*)&adj[(long)t * 4] = o;
}

extern "C" void kernel_launch(void* const* d_in, const int* in_sizes, int n_in,
                              void* d_out, int out_size, void* d_ws, size_t ws_size,
                              hipStream_t stream) {
    const float* x   = (const float*)d_in[0];
    const int*   ei  = (const int*)d_in[1];
    const int* batch = (const int*)d_in[2];
    const float* eps = (const float*)d_in[3];
    const float* W1  = (const float*)d_in[4];
    const float* b1  = (const float*)d_in[5];
    const float* W2  = (const float*)d_in[6];
    const float* b2  = (const float*)d_in[7];
    const float* Wmu = (const float*)d_in[8];
    const float* bmu = (const float*)d_in[9];
    const float* Wlv = (const float*)d_in[10];
    const float* blv = (const float*)d_in[11];
    const float* D1  = (const float*)d_in[12];
    const float* d1  = (const float*)d_in[13];
    const float* D2  = (const float*)d_in[14];
    const float* d2  = (const float*)d_in[15];
    const float* D3  = (const float*)d_in[16];
    const float* d3  = (const float*)d_in[17];

    const int* esrc = ei;
    const int* edst = ei + NE;

    float* out  = (float*)d_out;
    float* mu_o = out + 8388608;
    float* lv_o = mu_o + 32768;

    // --- CSR + small scratch lives in d_out (dead before the final writes) ---
    int*   colidx  = (int*)out;                 // 1,600,000
    int*   cnti    = colidx + 1600000;          // 100,000
    int*   rowptr  = cnti + 100000;             // 100,000
    int*   bsum    = rowptr + 100000;           // 128
    int*   boff    = bsum + 128;                // 128
    int*   seg_end = boff + 128;                // 512
    float* dinv    = (float*)(seg_end + 512);   // 100,000   (ends ~1.9M << 8.39M)

    // --- big buffers in ws ---
    float* ws   = (float*)d_ws;
    float* bufA = ws;                           // 12.8M floats
    float* bufB = bufA + 12800000;              // 12.8M floats
    int*   cur  = (int*)bufA;                   // alias: only during CSR build
    // decoder scratch aliases bufA (g2 dead after gather2)
    float* hg    = bufA;                        // 65,536
    float* zbuf  = bufA + 65536;                // 32,768
    float* p1    = bufA + 98304;                // 65,536
    float* p2    = bufA + 163840;               // 65,536
    float* probs = bufA + 229376;               // 4,161,536

    // ---- CSR build (once; edge_index is constant) ----
    hipMemsetAsync(cnti, 0, NN * sizeof(int), stream);
    k_deg<<<(NE + 255) / 256, 256, 0, stream>>>(edst, cnti);
    k_dinv<<<(NN + 255) / 256, 256, 0, stream>>>(cnti, dinv);
    k_scanA<<<98, 256, 0, stream>>>(cnti, rowptr, bsum);
    k_scanB<<<1, 128, 0, stream>>>(bsum, boff, 98);
    k_scanC<<<(NN + 255) / 256, 256, 0, stream>>>(rowptr, boff);
    hipMemsetAsync(cur, 0, NN * sizeof(int), stream);
    k_fill<<<(NE + 255) / 256, 256, 0, stream>>>(esrc, edst, rowptr, cur, colidx);
    k_segend<<<(NN + 255) / 256, 256, 0, stream>>>(batch, seg_end);

    // ---- conv1: g1 = (x@W1)*dinv -> bufA; h1 = relu((g1+gather)*dinv+b1) -> bufB
    k_gemm_scale<64><<<NN / 16, 256, 0, stream>>>(x, W1, dinv, bufA);
    k_gather<<<(NN + 3) / 4, 256, 0, stream>>>(rowptr, cnti, colidx, bufA, dinv, b1, bufB);

    // ---- conv2: g2 = (h1@W2)*dinv -> bufA; h2 -> bufB
    k_gemm_scale<128><<<NN / 16, 256, 0, stream>>>(bufB, W2, dinv, bufA);
    k_gather<<<(NN + 3) / 4, 256, 0, stream>>>(rowptr, cnti, colidx, bufA, dinv, b2, bufB);

    // ---- pool + heads + reparameterise ----
    k_poolmean<<<NG, 128, 0, stream>>>(bufB, seg_end, hg);
    k_head<<<NG, 64, 0, stream>>>(hg, Wmu, bmu, Wlv, blv, eps, mu_o, lv_o, zbuf);

    // ---- decoder ----
    k_mlp<<<NG, 128, 0, stream>>>(zbuf, 64, D1, d1, p1);
    k_mlp<<<NG, 128, 0, stream>>>(p1, 128, D2, d2, p2);
    dim3 g3(8, NG);
    k_dec3<<<g3, 256, 0, stream>>>(p2, D3, d3, probs);
    k_adj<<<8192, 256, 0, stream>>>(probs, out);
}

// Round 3
// 593.449 us; speedup vs baseline: 10.2864x; 1.2447x over previous
//
#include <hip/hip_runtime.h>

#define NN 100000
#define NE 1600000
#define NG 512
#define OUTS 8128

__device__ __forceinline__ unsigned pack_bf16x2(float a, float b) {
    unsigned ua = __float_as_uint(a);
    unsigned ub = __float_as_uint(b);
    ua = (ua + 0x7fffu + ((ua >> 16) & 1u)) >> 16;
    ub = (ub + 0x7fffu + ((ub >> 16) & 1u)) >> 16;
    return ua | (ub << 16);
}
__device__ __forceinline__ float bf16lo(unsigned u) { return __uint_as_float(u << 16); }
__device__ __forceinline__ float bf16hi(unsigned u) { return __uint_as_float(u & 0xffff0000u); }

// ---- int degree: cnt[dst] += 1 ----
__global__ __launch_bounds__(256) void k_deg(const int* __restrict__ dst, int* __restrict__ cnt) {
    int e = blockIdx.x * 256 + threadIdx.x;
    if (e < NE) atomicAdd(&cnt[dst[e]], 1);
}

// ---- dinv = rsqrt(deg + 1) ----
__global__ __launch_bounds__(256) void k_dinv(const int* __restrict__ cnt, float* __restrict__ dinv) {
    int i = blockIdx.x * 256 + threadIdx.x;
    if (i < NN) dinv[i] = rsqrtf((float)cnt[i] + 1.0f);
}

// ---- hierarchical exclusive scan: per-block (1024 elems) ----
__global__ __launch_bounds__(256) void k_scanA(const int* __restrict__ cnt, int* __restrict__ pre,
                                               int* __restrict__ bsum) {
    __shared__ int lds[256];
    int base = blockIdx.x * 1024 + threadIdx.x * 4;
    int v0 = 0, v1 = 0, v2 = 0, v3 = 0;
    if (base + 3 < NN) {
        int4 c = *(const int4*)&cnt[base];
        v0 = c.x; v1 = c.y; v2 = c.z; v3 = c.w;
    } else {
        if (base + 0 < NN) v0 = cnt[base + 0];
        if (base + 1 < NN) v1 = cnt[base + 1];
        if (base + 2 < NN) v2 = cnt[base + 2];
    }
    int s = v0 + v1 + v2 + v3;
    lds[threadIdx.x] = s;
    __syncthreads();
    for (int off = 1; off < 256; off <<= 1) {
        int t = (threadIdx.x >= off) ? lds[threadIdx.x - off] : 0;
        __syncthreads();
        lds[threadIdx.x] += t;
        __syncthreads();
    }
    int excl = lds[threadIdx.x] - s;
    if (threadIdx.x == 255) bsum[blockIdx.x] = lds[255];
    if (base < NN) {
        int p0 = excl, p1 = p0 + v0, p2 = p1 + v1, p3 = p2 + v2;
        if (base + 3 < NN) { int4 o = {p0, p1, p2, p3}; *(int4*)&pre[base] = o; }
        else {
            pre[base] = p0;
            if (base + 1 < NN) pre[base + 1] = p1;
            if (base + 2 < NN) pre[base + 2] = p2;
        }
    }
}

__global__ void k_scanB(const int* __restrict__ bsum, int* __restrict__ boff, int nb) {
    __shared__ int lds[128];
    int v = (threadIdx.x < nb) ? bsum[threadIdx.x] : 0;
    lds[threadIdx.x] = v;
    __syncthreads();
    for (int off = 1; off < 128; off <<= 1) {
        int t = (threadIdx.x >= off) ? lds[threadIdx.x - off] : 0;
        __syncthreads();
        lds[threadIdx.x] += t;
        __syncthreads();
    }
    if (threadIdx.x < nb) boff[threadIdx.x] = lds[threadIdx.x] - v;
}

__global__ __launch_bounds__(256) void k_scanC(int* __restrict__ pre, const int* __restrict__ boff) {
    int i = blockIdx.x * 256 + threadIdx.x;
    if (i < NN) pre[i] += boff[i >> 10];
}

// ---- counting-sort fill of CSR col indices ----
__global__ __launch_bounds__(256) void k_fill(const int* __restrict__ src, const int* __restrict__ dst,
        const int* __restrict__ rowptr, int* __restrict__ cur, int* __restrict__ colidx) {
    int e = blockIdx.x * 256 + threadIdx.x;
    if (e >= NE) return;
    int d = dst[e];
    int pos = atomicAdd(&cur[d], 1);
    colidx[rowptr[d] + pos] = src[e];
}

// ---- segment ends from sorted batch ----
__global__ __launch_bounds__(256) void k_segend(const int* __restrict__ batch, int* __restrict__ seg_end) {
    int i = blockIdx.x * 256 + threadIdx.x;
    if (i >= NN) return;
    int b = batch[i];
    int bn = (i == NN - 1) ? NG : batch[i + 1];
    for (int g = b; g < bn; ++g) seg_end[g] = i + 1;
    if (i == 0) {
        for (int g = 0; g < b; ++g) seg_end[g] = 0;
    }
}

// ---- gb[m][n] = bf16( dinv[m] * sum_k A[m][k] * W[k][n] );  N=128, packed x2 ----
template<int K>
__global__ __launch_bounds__(256) void k_gemm_scale(const float* __restrict__ A,
        const float* __restrict__ W, const float* __restrict__ dinv,
        unsigned* __restrict__ outb) {
    __shared__ __align__(16) float Wlds[64 * 128];
    int r  = threadIdx.x >> 4;
    int cg = threadIdx.x & 15;
    long row = (long)blockIdx.x * 16 + r;
    const float* a = &A[row * K];
    int c0 = cg * 8;
    float ax0=0,ax1=0,ax2=0,ax3=0,ay0=0,ay1=0,ay2=0,ay3=0;
    for (int kt = 0; kt < K; kt += 64) {
        __syncthreads();
        for (int i = threadIdx.x * 4; i < 64 * 128; i += 256 * 4)
            *(float4*)&Wlds[i] = *(const float4*)&W[kt * 128 + i];
        __syncthreads();
        #pragma unroll
        for (int kk = 0; kk < 64; ++kk) {
            float av = a[kt + kk];
            float4 w0 = *(const float4*)&Wlds[kk * 128 + c0];
            float4 w1 = *(const float4*)&Wlds[kk * 128 + c0 + 4];
            ax0 += av * w0.x; ax1 += av * w0.y; ax2 += av * w0.z; ax3 += av * w0.w;
            ay0 += av * w1.x; ay1 += av * w1.y; ay2 += av * w1.z; ay3 += av * w1.w;
        }
    }
    float d = dinv[row];
    uint4 o;
    o.x = pack_bf16x2(ax0 * d, ax1 * d);
    o.y = pack_bf16x2(ax2 * d, ax3 * d);
    o.z = pack_bf16x2(ay0 * d, ay1 * d);
    o.w = pack_bf16x2(ay2 * d, ay3 * d);
    *(uint4*)&outb[row * 64 + cg * 4] = o;
}

// ---- fused aggregate: out[n] = relu((g[n] + sum_{s in N(n)} g[s]) * dinv[n] + b) ----
// one wave per node; lane holds 2 channels packed bf16 (4B/lane/row)
__global__ __launch_bounds__(256) void k_gather(const int* __restrict__ rowptr,
        const int* __restrict__ cnti, const int* __restrict__ colidx,
        const unsigned* __restrict__ g, const float* __restrict__ dinv,
        const float* __restrict__ bias, float* __restrict__ out) {
    int node = blockIdx.x * 4 + (threadIdx.x >> 6);
    int lane = threadIdx.x & 63;
    unsigned us = g[(long)node * 64 + lane];
    float a0 = bf16lo(us), a1 = bf16hi(us);
    float b0 = 0.f, b1 = 0.f, c0 = 0.f, c1 = 0.f, d0 = 0.f, d1 = 0.f;
    int n = cnti[node];
    const int* ci = colidx + rowptr[node];
    int j = 0;
    for (; j + 4 <= n; j += 4) {
        int s0 = ci[j], s1 = ci[j + 1], s2 = ci[j + 2], s3 = ci[j + 3];
        unsigned u0 = g[(long)s0 * 64 + lane];
        unsigned u1 = g[(long)s1 * 64 + lane];
        unsigned u2 = g[(long)s2 * 64 + lane];
        unsigned u3 = g[(long)s3 * 64 + lane];
        a0 += bf16lo(u0); a1 += bf16hi(u0);
        b0 += bf16lo(u1); b1 += bf16hi(u1);
        c0 += bf16lo(u2); c1 += bf16hi(u2);
        d0 += bf16lo(u3); d1 += bf16hi(u3);
    }
    for (; j < n; ++j) {
        unsigned u0 = g[(long)ci[j] * 64 + lane];
        a0 += bf16lo(u0); a1 += bf16hi(u0);
    }
    a0 += b0 + c0 + d0;
    a1 += b1 + c1 + d1;
    float d = dinv[node];
    float2 bb = *(const float2*)&bias[lane * 2];
    float2 o = { fmaxf(fmaf(a0, d, bb.x), 0.f), fmaxf(fmaf(a1, d, bb.y), 0.f) };
    *(float2*)&out[(long)node * 128 + lane * 2] = o;
}

// ---- segmented mean pool: one block per graph, 128 ch ----
__global__ __launch_bounds__(128) void k_poolmean(const float* __restrict__ h,
        const int* __restrict__ seg_end, float* __restrict__ hg) {
    int g = blockIdx.x, t = threadIdx.x;
    int s = (g == 0) ? 0 : seg_end[g - 1];
    int e = seg_end[g];
    float acc = 0.f, acc2 = 0.f;
    int i = s;
    for (; i + 2 <= e; i += 2) {
        acc  += h[(long)i * 128 + t];
        acc2 += h[(long)(i + 1) * 128 + t];
    }
    if (i < e) acc += h[(long)i * 128 + t];
    acc += acc2;
    float inv = (e > s) ? 1.0f / (float)(e - s) : 0.f;
    hg[g * 128 + t] = acc * inv;
}

// ---- mu/logvar heads + reparameterise ----
__global__ __launch_bounds__(64) void k_head(const float* __restrict__ hg,
        const float* __restrict__ Wmu, const float* __restrict__ bmu,
        const float* __restrict__ Wlv, const float* __restrict__ blv,
        const float* __restrict__ eps, float* __restrict__ mu_o, float* __restrict__ lv_o,
        float* __restrict__ z) {
    __shared__ float row[128];
    int g = blockIdx.x, t = threadIdx.x;
    row[t]      = hg[g * 128 + t];
    row[t + 64] = hg[g * 128 + t + 64];
    __syncthreads();
    float mu = bmu[t], lv = blv[t];
    for (int k = 0; k < 128; ++k) {
        float rv = row[k];
        mu += rv * Wmu[k * 64 + t];
        lv += rv * Wlv[k * 64 + t];
    }
    mu_o[g * 64 + t] = mu;
    lv_o[g * 64 + t] = lv;
    z[g * 64 + t] = mu + eps[g * 64 + t] * expf(0.5f * lv);
}

// ---- small MLP layer: out[m] = relu(A[m] @ W + b), N=128 ----
__global__ __launch_bounds__(128) void k_mlp(const float* __restrict__ A, int K,
        const float* __restrict__ W, const float* __restrict__ b, float* __restrict__ out) {
    __shared__ float row[128];
    int m = blockIdx.x, t = threadIdx.x;
    if (t < K) row[t] = A[m * K + t];
    __syncthreads();
    float acc = b[t];
    for (int k = 0; k < K; ++k) acc += row[k] * W[k * 128 + t];
    out[m * 128 + t] = fmaxf(acc, 0.f);
}

// ---- probs = sigmoid(A @ D3 + d3); M=512 K=128 N=8128; 8-row m-tiles ----
__global__ __launch_bounds__(256) void k_dec3(const float* __restrict__ A,
        const float* __restrict__ W, const float* __restrict__ b, float* __restrict__ out) {
    __shared__ float alds[8][128];
    int m0 = blockIdx.y * 8;
    for (int i = threadIdx.x; i < 8 * 128; i += 256)
        alds[i >> 7][i & 127] = A[(m0 + (i >> 7)) * 128 + (i & 127)];
    __syncthreads();
    if (threadIdx.x >= 254) return;
    int c = blockIdx.x * 1016 + threadIdx.x * 4;
    float4 bb = *(const float4*)&b[c];
    float4 acc[8];
    #pragma unroll
    for (int r = 0; r < 8; ++r) acc[r] = bb;
    for (int k = 0; k < 128; ++k) {
        float4 w = *(const float4*)&W[(long)k * OUTS + c];
        #pragma unroll
        for (int r = 0; r < 8; ++r) {
            float a = alds[r][k];
            acc[r].x += a * w.x; acc[r].y += a * w.y;
            acc[r].z += a * w.z; acc[r].w += a * w.w;
        }
    }
    #pragma unroll
    for (int r = 0; r < 8; ++r) {
        float4 o;
        o.x = 1.f / (1.f + expf(-acc[r].x));
        o.y = 1.f / (1.f + expf(-acc[r].y));
        o.z = 1.f / (1.f + expf(-acc[r].z));
        o.w = 1.f / (1.f + expf(-acc[r].w));
        *(float4*)&out[(long)(m0 + r) * OUTS + c] = o;
    }
}

// ---- build symmetric adjacency from upper-tri probs ----
__global__ __launch_bounds__(256) void k_adj(const float* __restrict__ probs, float* __restrict__ adj) {
    int t = blockIdx.x * 256 + threadIdx.x;
    int g = t >> 12;
    int rem = t & 4095;
    int r = rem >> 5;
    int c0 = (rem & 31) * 4;
    const float* pg = &probs[g * OUTS];
    float4 o;
    float* op = (float*)&o;
    #pragma unroll
    for (int j = 0; j < 4; ++j) {
        int c = c0 + j;
        if (c == r) { op[j] = 0.f; continue; }
        int a = c < r ? c : r;
        int b = c < r ? r : c;
        int k = a * (255 - a) / 2 + (b - a - 1);
        op[j] = pg[k];
    }
    *(float4*)&adj[(long)t * 4] = o;
}

extern "C" void kernel_launch(void* const* d_in, const int* in_sizes, int n_in,
                              void* d_out, int out_size, void* d_ws, size_t ws_size,
                              hipStream_t stream) {
    const float* x   = (const float*)d_in[0];
    const int*   ei  = (const int*)d_in[1];
    const int* batch = (const int*)d_in[2];
    const float* eps = (const float*)d_in[3];
    const float* W1  = (const float*)d_in[4];
    const float* b1  = (const float*)d_in[5];
    const float* W2  = (const float*)d_in[6];
    const float* b2  = (const float*)d_in[7];
    const float* Wmu = (const float*)d_in[8];
    const float* bmu = (const float*)d_in[9];
    const float* Wlv = (const float*)d_in[10];
    const float* blv = (const float*)d_in[11];
    const float* D1  = (const float*)d_in[12];
    const float* d1  = (const float*)d_in[13];
    const float* D2  = (const float*)d_in[14];
    const float* d2  = (const float*)d_in[15];
    const float* D3  = (const float*)d_in[16];
    const float* d3  = (const float*)d_in[17];

    const int* esrc = ei;
    const int* edst = ei + NE;

    float* out  = (float*)d_out;
    float* mu_o = out + 8388608;
    float* lv_o = mu_o + 32768;

    // --- CSR + small scratch in d_out (dead before final writes) ---
    int*   colidx  = (int*)out;                 // 1,600,000
    int*   cnti    = colidx + 1600000;          // 100,000
    int*   rowptr  = cnti + 100000;             // 100,000
    int*   bsum    = rowptr + 100000;           // 128
    int*   boff    = bsum + 128;                // 128
    int*   seg_end = boff + 128;                // 512
    float* dinv    = (float*)(seg_end + 512);   // 100,000

    // --- big buffers in ws ---
    float* ws   = (float*)d_ws;
    float* bufA = ws;                           // 12.8M floats
    float* bufB = bufA + 12800000;              // 12.8M floats
    unsigned* gA = (unsigned*)bufA;             // bf16x2 packed, 6.4M uints
    int*   cur  = (int*)bufA;                   // alias: CSR build only
    // decoder scratch aliases bufA (g2 dead after gather2)
    float* hg    = bufA + 6553600;              // past gA region
    float* zbuf  = hg + 65536;
    float* p1    = zbuf + 32768;
    float* p2    = p1 + 65536;
    float* probs = p2 + 65536;                  // 4,161,536 (fits in bufA's 12.8M)

    // ---- CSR build ----
    hipMemsetAsync(cnti, 0, NN * sizeof(int), stream);
    k_deg<<<(NE + 255) / 256, 256, 0, stream>>>(edst, cnti);
    k_dinv<<<(NN + 255) / 256, 256, 0, stream>>>(cnti, dinv);
    k_scanA<<<98, 256, 0, stream>>>(cnti, rowptr, bsum);
    k_scanB<<<1, 128, 0, stream>>>(bsum, boff, 98);
    k_scanC<<<(NN + 255) / 256, 256, 0, stream>>>(rowptr, boff);
    hipMemsetAsync(cur, 0, NN * sizeof(int), stream);
    k_fill<<<(NE + 255) / 256, 256, 0, stream>>>(esrc, edst, rowptr, cur, colidx);
    k_segend<<<(NN + 255) / 256, 256, 0, stream>>>(batch, seg_end);

    // ---- conv1: g1 = bf16((x@W1)*dinv) -> gA; h1 = relu((Σ+self)*dinv+b1) -> bufB
    k_gemm_scale<64><<<NN / 16, 256, 0, stream>>>(x, W1, dinv, gA);
    k_gather<<<NN / 4, 256, 0, stream>>>(rowptr, cnti, colidx, gA, dinv, b1, bufB);

    // ---- conv2: g2 = bf16((h1@W2)*dinv) -> gA; h2 -> bufB
    k_gemm_scale<128><<<NN / 16, 256, 0, stream>>>(bufB, W2, dinv, gA);
    k_gather<<<NN / 4, 256, 0, stream>>>(rowptr, cnti, colidx, gA, dinv, b2, bufB);

    // ---- pool + heads ----
    k_poolmean<<<NG, 128, 0, stream>>>(bufB, seg_end, hg);
    k_head<<<NG, 64, 0, stream>>>(hg, Wmu, bmu, Wlv, blv, eps, mu_o, lv_o, zbuf);

    // ---- decoder ----
    k_mlp<<<NG, 128, 0, stream>>>(zbuf, 64, D1, d1, p1);
    k_mlp<<<NG, 128, 0, stream>>>(p1, 128, D2, d2, p2);
    dim3 g3(8, 64);
    k_dec3<<<g3, 256, 0, stream>>>(p2, D3, d3, probs);
    k_adj<<<8192, 256, 0, stream>>>(probs, out);
}

// Round 4
// 472.294 us; speedup vs baseline: 12.9251x; 1.2565x over previous
//
#include <hip/hip_runtime.h>

#define NN 100000
#define NE 1600000
#define NG 512
#define OUTS 8128

typedef short bf16x8 __attribute__((ext_vector_type(8)));
typedef float f32x4 __attribute__((ext_vector_type(4)));

__device__ __forceinline__ unsigned pack_bf16x2(float a, float b) {
    unsigned ua = __float_as_uint(a);
    unsigned ub = __float_as_uint(b);
    ua = (ua + 0x7fffu + ((ua >> 16) & 1u)) >> 16;
    ub = (ub + 0x7fffu + ((ub >> 16) & 1u)) >> 16;
    return ua | (ub << 16);
}
__device__ __forceinline__ unsigned short f2bf(float f) {
    unsigned u = __float_as_uint(f);
    u = (u + 0x7fffu + ((u >> 16) & 1u)) >> 16;
    return (unsigned short)u;
}
__device__ __forceinline__ float bf16lo(unsigned u) { return __uint_as_float(u << 16); }
__device__ __forceinline__ float bf16hi(unsigned u) { return __uint_as_float(u & 0xffff0000u); }

// ---- int degree: cnt[dst] += 1 ----
__global__ __launch_bounds__(256) void k_deg(const int* __restrict__ dst, int* __restrict__ cnt) {
    int e = blockIdx.x * 256 + threadIdx.x;
    if (e < NE) atomicAdd(&cnt[dst[e]], 1);
}

// ---- dinv = rsqrt(deg + 1) ----
__global__ __launch_bounds__(256) void k_dinv(const int* __restrict__ cnt, float* __restrict__ dinv) {
    int i = blockIdx.x * 256 + threadIdx.x;
    if (i < NN) dinv[i] = rsqrtf((float)cnt[i] + 1.0f);
}

// ---- hierarchical exclusive scan ----
__global__ __launch_bounds__(256) void k_scanA(const int* __restrict__ cnt, int* __restrict__ pre,
                                               int* __restrict__ bsum) {
    __shared__ int lds[256];
    int base = blockIdx.x * 1024 + threadIdx.x * 4;
    int v0 = 0, v1 = 0, v2 = 0, v3 = 0;
    if (base + 3 < NN) {
        int4 c = *(const int4*)&cnt[base];
        v0 = c.x; v1 = c.y; v2 = c.z; v3 = c.w;
    } else {
        if (base + 0 < NN) v0 = cnt[base + 0];
        if (base + 1 < NN) v1 = cnt[base + 1];
        if (base + 2 < NN) v2 = cnt[base + 2];
    }
    int s = v0 + v1 + v2 + v3;
    lds[threadIdx.x] = s;
    __syncthreads();
    for (int off = 1; off < 256; off <<= 1) {
        int t = (threadIdx.x >= off) ? lds[threadIdx.x - off] : 0;
        __syncthreads();
        lds[threadIdx.x] += t;
        __syncthreads();
    }
    int excl = lds[threadIdx.x] - s;
    if (threadIdx.x == 255) bsum[blockIdx.x] = lds[255];
    if (base < NN) {
        int p0 = excl, p1 = p0 + v0, p2 = p1 + v1, p3 = p2 + v2;
        if (base + 3 < NN) { int4 o = {p0, p1, p2, p3}; *(int4*)&pre[base] = o; }
        else {
            pre[base] = p0;
            if (base + 1 < NN) pre[base + 1] = p1;
            if (base + 2 < NN) pre[base + 2] = p2;
        }
    }
}

__global__ void k_scanB(const int* __restrict__ bsum, int* __restrict__ boff, int nb) {
    __shared__ int lds[128];
    int v = (threadIdx.x < nb) ? bsum[threadIdx.x] : 0;
    lds[threadIdx.x] = v;
    __syncthreads();
    for (int off = 1; off < 128; off <<= 1) {
        int t = (threadIdx.x >= off) ? lds[threadIdx.x - off] : 0;
        __syncthreads();
        lds[threadIdx.x] += t;
        __syncthreads();
    }
    if (threadIdx.x < nb) boff[threadIdx.x] = lds[threadIdx.x] - v;
}

__global__ __launch_bounds__(256) void k_scanC(int* __restrict__ pre, const int* __restrict__ boff) {
    int i = blockIdx.x * 256 + threadIdx.x;
    if (i < NN) pre[i] += boff[i >> 10];
}

// ---- counting-sort fill of CSR col indices ----
__global__ __launch_bounds__(256) void k_fill(const int* __restrict__ src, const int* __restrict__ dst,
        const int* __restrict__ rowptr, int* __restrict__ cur, int* __restrict__ colidx) {
    int e = blockIdx.x * 256 + threadIdx.x;
    if (e >= NE) return;
    int d = dst[e];
    int pos = atomicAdd(&cur[d], 1);
    colidx[rowptr[d] + pos] = src[e];
}

// ---- segment ends from sorted batch ----
__global__ __launch_bounds__(256) void k_segend(const int* __restrict__ batch, int* __restrict__ seg_end) {
    int i = blockIdx.x * 256 + threadIdx.x;
    if (i >= NN) return;
    int b = batch[i];
    int bn = (i == NN - 1) ? NG : batch[i + 1];
    for (int g = b; g < bn; ++g) seg_end[g] = i + 1;
    if (i == 0) {
        for (int g = 0; g < b; ++g) seg_end[g] = 0;
    }
}

// ---- W[K][128] fp32 -> WT[128][K] bf16 ----
template<int K>
__global__ __launch_bounds__(256) void k_wt(const float* __restrict__ W, unsigned short* __restrict__ wt) {
    int e = blockIdx.x * 256 + threadIdx.x;   // < 128*K
    int n = e / K, k = e - n * K;
    wt[e] = f2bf(W[k * 128 + n]);
}

// ---- MFMA GEMM: outb[m][n] = bf16(dinv[m] * sum_k A[m][k]*W[k][n]), N=128 ----
// 4 waves/block, 64 rows/block; WT staged in LDS with XOR swizzle (T2/G4)
template<int K, bool AF32>
__global__ __launch_bounds__(256) void k_gemm_mfma(const void* __restrict__ Ap,
        const unsigned short* __restrict__ wt, const float* __restrict__ dinv,
        unsigned short* __restrict__ outb) {
    constexpr int KS = K / 32;
    constexpr int SLOTS = K / 8;                 // 16B slots per WT row
    __shared__ __align__(16) unsigned short wlds[128 * K];
    char* lb = (char*)wlds;
    for (int c = threadIdx.x; c < 128 * SLOTS; c += 256) {
        int n = c / SLOTS, s = c - n * SLOTS;
        *(uint4*)(lb + n * (2 * K) + ((s ^ (n & 7)) << 4)) = *(const uint4*)(wt + c * 8);
    }
    __syncthreads();
    int lane = threadIdx.x & 63;
    int w = threadIdx.x >> 6;
    int r0 = blockIdx.x * 64 + w * 16;
    int arow = r0 + (lane & 15);
    if (arow >= NN) arow = NN - 1;
    bf16x8 af[KS];
    if (AF32) {
        const float* Af = (const float*)Ap;
        #pragma unroll
        for (int ks = 0; ks < KS; ++ks) {
            const float* p = &Af[(long)arow * K + ks * 32 + (lane >> 4) * 8];
            float4 f0 = *(const float4*)p;
            float4 f1 = *(const float4*)(p + 4);
            union { uint4 u; bf16x8 v; } cv;
            cv.u.x = pack_bf16x2(f0.x, f0.y);
            cv.u.y = pack_bf16x2(f0.z, f0.w);
            cv.u.z = pack_bf16x2(f1.x, f1.y);
            cv.u.w = pack_bf16x2(f1.z, f1.w);
            af[ks] = cv.v;
        }
    } else {
        const unsigned short* Ab = (const unsigned short*)Ap;
        #pragma unroll
        for (int ks = 0; ks < KS; ++ks)
            af[ks] = *(const bf16x8*)&Ab[(long)arow * K + ks * 32 + (lane >> 4) * 8];
    }
    f32x4 acc[8];
    #pragma unroll
    for (int t = 0; t < 8; ++t) acc[t] = (f32x4){0.f, 0.f, 0.f, 0.f};
    #pragma unroll
    for (int ks = 0; ks < KS; ++ks) {
        #pragma unroll
        for (int t = 0; t < 8; ++t) {
            int n = t * 16 + (lane & 15);
            int slot = ks * 4 + (lane >> 4);
            bf16x8 bf = *(const bf16x8*)(lb + n * (2 * K) + ((slot ^ (n & 7)) << 4));
            acc[t] = __builtin_amdgcn_mfma_f32_16x16x32_bf16(af[ks], bf, acc[t], 0, 0, 0);
        }
    }
    float d[4];
    #pragma unroll
    for (int r = 0; r < 4; ++r) {
        int row = r0 + (lane >> 4) * 4 + r;
        d[r] = dinv[row < NN ? row : NN - 1];
    }
    #pragma unroll
    for (int t = 0; t < 8; ++t) {
        #pragma unroll
        for (int r = 0; r < 4; ++r) {
            long row = r0 + (lane >> 4) * 4 + r;   // padded buffer: store OK
            outb[row * 128 + t * 16 + (lane & 15)] = f2bf(acc[t][r] * d[r]);
        }
    }
}

// ---- fused aggregate -> packed bf16: out = bf16(relu((g[n]+Σ g[s])*dinv + b)) ----
__global__ __launch_bounds__(256) void k_gather(const int* __restrict__ rowptr,
        const int* __restrict__ cnti, const int* __restrict__ colidx,
        const unsigned* __restrict__ g, const float* __restrict__ dinv,
        const float* __restrict__ bias, unsigned* __restrict__ outb) {
    int node = blockIdx.x * 4 + (threadIdx.x >> 6);
    int lane = threadIdx.x & 63;
    unsigned us = g[(long)node * 64 + lane];
    float a0 = bf16lo(us), a1 = bf16hi(us);
    float b0 = 0.f, b1 = 0.f, c0 = 0.f, c1 = 0.f, d0 = 0.f, d1 = 0.f;
    int n = cnti[node];
    const int* ci = colidx + rowptr[node];
    int j = 0;
    for (; j + 4 <= n; j += 4) {
        int s0 = ci[j], s1 = ci[j + 1], s2 = ci[j + 2], s3 = ci[j + 3];
        unsigned u0 = g[(long)s0 * 64 + lane];
        unsigned u1 = g[(long)s1 * 64 + lane];
        unsigned u2 = g[(long)s2 * 64 + lane];
        unsigned u3 = g[(long)s3 * 64 + lane];
        a0 += bf16lo(u0); a1 += bf16hi(u0);
        b0 += bf16lo(u1); b1 += bf16hi(u1);
        c0 += bf16lo(u2); c1 += bf16hi(u2);
        d0 += bf16lo(u3); d1 += bf16hi(u3);
    }
    for (; j < n; ++j) {
        unsigned u0 = g[(long)ci[j] * 64 + lane];
        a0 += bf16lo(u0); a1 += bf16hi(u0);
    }
    a0 += b0 + c0 + d0;
    a1 += b1 + c1 + d1;
    float d = dinv[node];
    float2 bb = *(const float2*)&bias[lane * 2];
    float o0 = fmaxf(fmaf(a0, d, bb.x), 0.f);
    float o1 = fmaxf(fmaf(a1, d, bb.y), 0.f);
    outb[(long)node * 64 + lane] = pack_bf16x2(o0, o1);
}

// ---- segmented mean pool over bf16 h2: one block(64thr) per graph ----
__global__ __launch_bounds__(64) void k_poolmean(const unsigned* __restrict__ h,
        const int* __restrict__ seg_end, float* __restrict__ hg) {
    int g = blockIdx.x, t = threadIdx.x;
    int s = (g == 0) ? 0 : seg_end[g - 1];
    int e = seg_end[g];
    float a0 = 0.f, a1 = 0.f, b0 = 0.f, b1 = 0.f;
    int i = s;
    for (; i + 2 <= e; i += 2) {
        unsigned u0 = h[(long)i * 64 + t];
        unsigned u1 = h[(long)(i + 1) * 64 + t];
        a0 += bf16lo(u0); a1 += bf16hi(u0);
        b0 += bf16lo(u1); b1 += bf16hi(u1);
    }
    if (i < e) {
        unsigned u0 = h[(long)i * 64 + t];
        a0 += bf16lo(u0); a1 += bf16hi(u0);
    }
    a0 += b0; a1 += b1;
    float inv = (e > s) ? 1.0f / (float)(e - s) : 0.f;
    float2 o = { a0 * inv, a1 * inv };
    *(float2*)&hg[g * 128 + t * 2] = o;
}

// ---- mu/logvar heads + reparameterise ----
__global__ __launch_bounds__(64) void k_head(const float* __restrict__ hg,
        const float* __restrict__ Wmu, const float* __restrict__ bmu,
        const float* __restrict__ Wlv, const float* __restrict__ blv,
        const float* __restrict__ eps, float* __restrict__ mu_o, float* __restrict__ lv_o,
        float* __restrict__ z) {
    __shared__ float row[128];
    int g = blockIdx.x, t = threadIdx.x;
    row[t]      = hg[g * 128 + t];
    row[t + 64] = hg[g * 128 + t + 64];
    __syncthreads();
    float mu = bmu[t], lv = blv[t];
    for (int k = 0; k < 128; ++k) {
        float rv = row[k];
        mu += rv * Wmu[k * 64 + t];
        lv += rv * Wlv[k * 64 + t];
    }
    mu_o[g * 64 + t] = mu;
    lv_o[g * 64 + t] = lv;
    z[g * 64 + t] = mu + eps[g * 64 + t] * expf(0.5f * lv);
}

// ---- small MLP layer ----
__global__ __launch_bounds__(128) void k_mlp(const float* __restrict__ A, int K,
        const float* __restrict__ W, const float* __restrict__ b, float* __restrict__ out) {
    __shared__ float row[128];
    int m = blockIdx.x, t = threadIdx.x;
    if (t < K) row[t] = A[m * K + t];
    __syncthreads();
    float acc = b[t];
    for (int k = 0; k < K; ++k) acc += row[k] * W[k * 128 + t];
    out[m * 128 + t] = fmaxf(acc, 0.f);
}

// ---- probs = sigmoid(A @ D3 + d3); 8-row m-tiles ----
__global__ __launch_bounds__(256) void k_dec3(const float* __restrict__ A,
        const float* __restrict__ W, const float* __restrict__ b, float* __restrict__ out) {
    __shared__ float alds[8][128];
    int m0 = blockIdx.y * 8;
    for (int i = threadIdx.x; i < 8 * 128; i += 256)
        alds[i >> 7][i & 127] = A[(m0 + (i >> 7)) * 128 + (i & 127)];
    __syncthreads();
    if (threadIdx.x >= 254) return;
    int c = blockIdx.x * 1016 + threadIdx.x * 4;
    float4 bb = *(const float4*)&b[c];
    float4 acc[8];
    #pragma unroll
    for (int r = 0; r < 8; ++r) acc[r] = bb;
    for (int k = 0; k < 128; ++k) {
        float4 w = *(const float4*)&W[(long)k * OUTS + c];
        #pragma unroll
        for (int r = 0; r < 8; ++r) {
            float a = alds[r][k];
            acc[r].x += a * w.x; acc[r].y += a * w.y;
            acc[r].z += a * w.z; acc[r].w += a * w.w;
        }
    }
    #pragma unroll
    for (int r = 0; r < 8; ++r) {
        float4 o;
        o.x = 1.f / (1.f + expf(-acc[r].x));
        o.y = 1.f / (1.f + expf(-acc[r].y));
        o.z = 1.f / (1.f + expf(-acc[r].z));
        o.w = 1.f / (1.f + expf(-acc[r].w));
        *(float4*)&out[(long)(m0 + r) * OUTS + c] = o;
    }
}

// ---- build symmetric adjacency ----
__global__ __launch_bounds__(256) void k_adj(const float* __restrict__ probs, float* __restrict__ adj) {
    int t = blockIdx.x * 256 + threadIdx.x;
    int g = t >> 12;
    int rem = t & 4095;
    int r = rem >> 5;
    int c0 = (rem & 31) * 4;
    const float* pg = &probs[g * OUTS];
    float4 o;
    float* op = (float*)&o;
    #pragma unroll
    for (int j = 0; j < 4; ++j) {
        int c = c0 + j;
        if (c == r) { op[j] = 0.f; continue; }
        int a = c < r ? c : r;
        int b = c < r ? r : c;
        int k = a * (255 - a) / 2 + (b - a - 1);
        op[j] = pg[k];
    }
    *(float4*)&adj[(long)t * 4] = o;
}

extern "C" void kernel_launch(void* const* d_in, const int* in_sizes, int n_in,
                              void* d_out, int out_size, void* d_ws, size_t ws_size,
                              hipStream_t stream) {
    const float* x   = (const float*)d_in[0];
    const int*   ei  = (const int*)d_in[1];
    const int* batch = (const int*)d_in[2];
    const float* eps = (const float*)d_in[3];
    const float* W1  = (const float*)d_in[4];
    const float* b1  = (const float*)d_in[5];
    const float* W2  = (const float*)d_in[6];
    const float* b2  = (const float*)d_in[7];
    const float* Wmu = (const float*)d_in[8];
    const float* bmu = (const float*)d_in[9];
    const float* Wlv = (const float*)d_in[10];
    const float* blv = (const float*)d_in[11];
    const float* D1  = (const float*)d_in[12];
    const float* d1  = (const float*)d_in[13];
    const float* D2  = (const float*)d_in[14];
    const float* d2  = (const float*)d_in[15];
    const float* D3  = (const float*)d_in[16];
    const float* d3  = (const float*)d_in[17];

    const int* esrc = ei;
    const int* edst = ei + NE;

    float* out  = (float*)d_out;
    float* mu_o = out + 8388608;
    float* lv_o = mu_o + 32768;

    // --- CSR + small scratch in d_out (dead before final writes) ---
    int*   colidx  = (int*)out;                 // 1,600,000
    int*   cnti    = colidx + 1600000;          // 100,000
    int*   rowptr  = cnti + 100000;             // 100,000
    int*   bsum    = rowptr + 100000;           // 128
    int*   boff    = bsum + 128;                // 128
    int*   seg_end = boff + 128;                // 512
    float* dinv    = (float*)(seg_end + 512);   // 100,000

    // --- ws layout (float units) ---
    float* ws = (float*)d_ws;
    unsigned short* gA16 = (unsigned short*)ws;           // 100032x128 u16 (25.6MB)
    unsigned* gAu        = (unsigned*)ws;                 // uint view
    unsigned* h1b  = (unsigned*)(ws + 6402560);           // 100000x64 uint (25.6MB)
    unsigned* h2b  = (unsigned*)(ws + 12802560);          // 100000x64 uint (25.6MB)
    unsigned short* wt1 = (unsigned short*)(ws + 19202560); // 128x64 u16
    unsigned short* wt2 = (unsigned short*)(ws + 19206656); // 128x128 u16
    int* cur = (int*)gA16;                                // alias: CSR build only
    // decoder scratch aliases h1b (dead after gemm2)
    float* hg    = ws + 6402560;
    float* zbuf  = hg + 65536;
    float* p1    = zbuf + 32768;
    float* p2    = p1 + 65536;
    float* probs = p2 + 65536;                            // 4,161,536 floats

    // ---- CSR build ----
    hipMemsetAsync(cnti, 0, NN * sizeof(int), stream);
    k_deg<<<(NE + 255) / 256, 256, 0, stream>>>(edst, cnti);
    k_dinv<<<(NN + 255) / 256, 256, 0, stream>>>(cnti, dinv);
    k_scanA<<<98, 256, 0, stream>>>(cnti, rowptr, bsum);
    k_scanB<<<1, 128, 0, stream>>>(bsum, boff, 98);
    k_scanC<<<(NN + 255) / 256, 256, 0, stream>>>(rowptr, boff);
    hipMemsetAsync(cur, 0, NN * sizeof(int), stream);
    k_fill<<<(NE + 255) / 256, 256, 0, stream>>>(esrc, edst, rowptr, cur, colidx);
    k_segend<<<(NN + 255) / 256, 256, 0, stream>>>(batch, seg_end);

    // ---- weight transposes to bf16 ----
    k_wt<64><<<32, 256, 0, stream>>>(W1, wt1);
    k_wt<128><<<64, 256, 0, stream>>>(W2, wt2);

    // ---- conv1: g1 = bf16((x@W1)*dinv) -> gA16; h1 = bf16(relu((Σ+self)*dinv+b1)) -> h1b
    k_gemm_mfma<64, true><<<1563, 256, 0, stream>>>(x, wt1, dinv, gA16);
    k_gather<<<NN / 4, 256, 0, stream>>>(rowptr, cnti, colidx, gAu, dinv, b1, h1b);

    // ---- conv2: g2 = bf16((h1@W2)*dinv) -> gA16; h2 -> h2b
    k_gemm_mfma<128, false><<<1563, 256, 0, stream>>>(h1b, wt2, dinv, gA16);
    k_gather<<<NN / 4, 256, 0, stream>>>(rowptr, cnti, colidx, gAu, dinv, b2, h2b);

    // ---- pool + heads ----
    k_poolmean<<<NG, 64, 0, stream>>>(h2b, seg_end, hg);
    k_head<<<NG, 64, 0, stream>>>(hg, Wmu, bmu, Wlv, blv, eps, mu_o, lv_o, zbuf);

    // ---- decoder ----
    k_mlp<<<NG, 128, 0, stream>>>(zbuf, 64, D1, d1, p1);
    k_mlp<<<NG, 128, 0, stream>>>(p1, 128, D2, d2, p2);
    dim3 g3(8, 64);
    k_dec3<<<g3, 256, 0, stream>>>(p2, D3, d3, probs);
    k_adj<<<8192, 256, 0, stream>>>(probs, out);
}